// Round 9
// baseline (346.992 us; speedup 1.0000x reference)
//
#include <hip/hip_runtime.h>

// VanillaRNN: S=512, I=1, H=256, C=10, B=2048, fp32 in/out.
// R9: R8 + tail-pack. R8 proved conflicts (now 5.2e6 ~ 79 cyc/step) were
// not binding; step = LDS phase (~850 cyc) + phase-locked serial tail
// (~500 cyc: 8-deep MFMA chain 160 + trans 256 + VALU + barrier). R9
// shrinks the tail: (a) dual accumulators per m-tile (ks even/odd) halve
// the MFMA dep chain; (b) next-step C-operand (b_h + W_hx*x_{t+1}) is
// computed in the read-latency shadow of the current step.
// Layout (R8, validated): 16B-granule G of batch-row n at slot G^n ->
// per-oct injective, residual 2-way only (free, m136). Reads 8x b128/wave,
// writes 2x b64/wave. 128 blocks x 8 waves (2/SIMD TLP), 2 m-tiles/wave,
// weights pre-scaled by 2*log2e, tanh = 1 - 2*rcp(exp2(s)+1).
// waves_per_eu(2,2): 256-VGPR budget, no spill (R1/R2 lesson).

#define SEQ   512
#define HID   256
#define NCLS  10
#define BN    16      // batch per block
#define NT    512     // 8 waves

typedef _Float16 f16x8 __attribute__((ext_vector_type(8)));
typedef _Float16 f16x4 __attribute__((ext_vector_type(4)));
typedef float    f32x4 __attribute__((ext_vector_type(4)));

__global__ __launch_bounds__(NT)
__attribute__((amdgpu_waves_per_eu(2, 2)))
void rnn_mfma(
    const float* __restrict__ x,     // [B, S]
    const float* __restrict__ W_hx,  // [H]
    const float* __restrict__ W_hh,  // [H, H]
    const float* __restrict__ W_ph,  // [C, H]
    const float* __restrict__ b_h,   // [H]
    const float* __restrict__ b_p,   // [C]
    float* __restrict__ out)         // [B, C]
{
    // hT[buf][n][.]: 16B-granule G of batch-row n at physical slot G^n
    __shared__ __align__(16) _Float16 hT[2][BN][HID];    // 16 KB
    __shared__ __align__(16) float xs[SEQ + 2][BN];      // 32.9 KB

    const int tid  = threadIdx.x;
    const int lane = tid & 63;
    const int wave = tid >> 6;       // 0..7
    const int n16  = lane & 15;
    const int quad = lane >> 4;      // 0..3
    const int b0   = blockIdx.x * BN;

    const float SC = 2.885390081777926814f;   // 2*log2(e)

    // ---- A-frags: rows [wave*32, wave*32+32), pre-scaled by SC, f16 ----
    // A[m = n16][k = quad*8 + j]
    f16x8 afrag[2][8];
#pragma unroll
    for (int mt = 0; mt < 2; ++mt) {
        const int row = wave * 32 + mt * 16 + n16;
#pragma unroll
        for (int ks = 0; ks < 8; ++ks) {
            const float4* p = (const float4*)&W_hh[row * HID + ks * 32 + quad * 8];
            float4 u = p[0], v = p[1];
            f16x8 a;
            a[0] = (_Float16)(SC * u.x); a[1] = (_Float16)(SC * u.y);
            a[2] = (_Float16)(SC * u.z); a[3] = (_Float16)(SC * u.w);
            a[4] = (_Float16)(SC * v.x); a[5] = (_Float16)(SC * v.y);
            a[6] = (_Float16)(SC * v.z); a[7] = (_Float16)(SC * v.w);
            afrag[mt][ks] = a;
        }
    }
    // D rows for this lane: row = wave*32 + mt*16 + quad*4 + r
    f32x4 bias[2], wxv[2];
#pragma unroll
    for (int mt = 0; mt < 2; ++mt)
#pragma unroll
        for (int r = 0; r < 4; ++r) {
            const int row = wave * 32 + mt * 16 + quad * 4 + r;
            bias[mt][r] = SC * b_h[row];
            wxv[mt][r]  = SC * W_hx[row];
        }

    // ---- swizzled byte offsets ----
    // read ks (b128): granule16 G = 4ks+quad of row n16 at slot16 = G^n16
    int roff[8];
#pragma unroll
    for (int ks = 0; ks < 8; ++ks)
        roff[ks] = n16 * 512 + (((4 * ks + quad) ^ n16) << 4);
    // write mt (b64): granule64 gw = 8*wave+4*mt+quad at slot64 = gw^(n16<<1)
    int woff[2];
#pragma unroll
    for (int mt = 0; mt < 2; ++mt)
        woff[mt] = n16 * 512 + (((8 * wave + 4 * mt + quad) ^ (n16 << 1)) << 3);

    // ---- stage xs[t][n] = x[b0+n][t] ----
    for (int i = tid; i < BN * SEQ / 4; i += NT) {
        const int n = i >> 7, t4 = (i & 127) * 4;
        float4 v = *(const float4*)&x[(b0 + n) * SEQ + t4];
        xs[t4 + 0][n] = v.x; xs[t4 + 1][n] = v.y;
        xs[t4 + 2][n] = v.z; xs[t4 + 3][n] = v.w;
    }
    // ---- h0 = 0 (buffer 0 only; buffer 1 fully written each odd step) ----
    for (int i = tid; i < BN * HID / 2; i += NT) ((float*)hT[0])[i] = 0.0f;
    __syncthreads();

    // C-operand for step 0, prepared ahead (b_h + W_hx * x_0, SC-scaled)
    f32x4 c0[2];
    {
        const float xv0 = xs[0][n16];
#pragma unroll
        for (int mt = 0; mt < 2; ++mt)
#pragma unroll
            for (int r = 0; r < 4; ++r)
                c0[mt][r] = fmaf(wxv[mt][r], xv0, bias[mt][r]);
    }

#define RNN_STEP(T, RD, WR)                                                   \
    {                                                                         \
        const char* hb = (const char*)hT[RD];                                 \
        f16x8 bfr[8];                                                         \
        _Pragma("unroll")                                                     \
        for (int ks = 0; ks < 8; ++ks)                                        \
            bfr[ks] = *(const f16x8*)(hb + roff[ks]);  /* ds_read_b128 */     \
        /* next-step C-operand in the read-latency shadow */                  \
        f32x4 c1[2];                                                          \
        {                                                                     \
            const float xn = xs[(T) + 1][n16];                                \
            _Pragma("unroll")                                                 \
            for (int mt = 0; mt < 2; ++mt)                                    \
                _Pragma("unroll")                                             \
                for (int r = 0; r < 4; ++r)                                   \
                    c1[mt][r] = fmaf(wxv[mt][r], xn, bias[mt][r]);            \
        }                                                                     \
        /* dual-accumulator chains: ks even -> accA (seeded with c0),      */ \
        /* ks odd -> accB (seeded with 0); 4-deep chains instead of 8.     */ \
        f32x4 accA[2], accB[2];                                               \
        const f32x4 zero = {0.f, 0.f, 0.f, 0.f};                              \
        _Pragma("unroll")                                                     \
        for (int mt = 0; mt < 2; ++mt) {                                      \
            accA[mt] = __builtin_amdgcn_mfma_f32_16x16x32_f16(                \
                afrag[mt][0], bfr[0], c0[mt], 0, 0, 0);                       \
            accB[mt] = __builtin_amdgcn_mfma_f32_16x16x32_f16(                \
                afrag[mt][1], bfr[1], zero, 0, 0, 0);                         \
        }                                                                     \
        _Pragma("unroll")                                                     \
        for (int kp = 1; kp < 4; ++kp)                                        \
            _Pragma("unroll")                                                 \
            for (int mt = 0; mt < 2; ++mt) {                                  \
                accA[mt] = __builtin_amdgcn_mfma_f32_16x16x32_f16(            \
                    afrag[mt][2 * kp], bfr[2 * kp], accA[mt], 0, 0, 0);       \
                accB[mt] = __builtin_amdgcn_mfma_f32_16x16x32_f16(            \
                    afrag[mt][2 * kp + 1], bfr[2 * kp + 1], accB[mt], 0, 0, 0);\
            }                                                                 \
        char* wb = (char*)hT[WR];                                             \
        _Pragma("unroll")                                                     \
        for (int mt = 0; mt < 2; ++mt) {                                      \
            f16x4 h4;                                                         \
            _Pragma("unroll")                                                 \
            for (int r = 0; r < 4; ++r) {                                     \
                float s  = accA[mt][r] + accB[mt][r];                         \
                float ex = __builtin_amdgcn_exp2f(s);                         \
                float rc = __builtin_amdgcn_rcpf(ex + 1.0f);                  \
                h4[r] = (_Float16)(1.0f - 2.0f * rc);                         \
            }                                                                 \
            *(f16x4*)(wb + woff[mt]) = h4;            /* ds_write_b64 */      \
        }                                                                     \
        c0[0] = c1[0]; c0[1] = c1[1];                                         \
        __syncthreads();                                                      \
    }

    for (int t = 0; t < SEQ; t += 2) {
        RNN_STEP(t, 0, 1);
        RNN_STEP(t + 1, 1, 0);
    }
#undef RNN_STEP

    // ---- output: out[b][c] = b_p[c] + sum_j W_ph[c][j] * h_final[j][b] ----
    // final h in hT[0]; f16 j of row b at ((j>>2)^(2b))*4 + (j&3)
    if (tid < BN * NCLS) {
        const int b = tid / NCLS, c = tid % NCLS;
        float sum = b_p[c];
        const _Float16* hp = hT[0][b];
        for (int j = 0; j < HID; ++j) {
            const int ph = ((((j >> 2) ^ (2 * b)) << 2) | (j & 3));
            sum += W_ph[c * HID + j] * (float)hp[ph];
        }
        out[(b0 + b) * NCLS + c] = sum;
    }
}

extern "C" void kernel_launch(void* const* d_in, const int* in_sizes, int n_in,
                              void* d_out, int out_size, void* d_ws, size_t ws_size,
                              hipStream_t stream) {
    const float* x    = (const float*)d_in[0];
    const float* W_hx = (const float*)d_in[1];
    const float* W_hh = (const float*)d_in[2];
    const float* W_ph = (const float*)d_in[3];
    const float* b_h  = (const float*)d_in[4];
    const float* b_p  = (const float*)d_in[5];
    float* out = (float*)d_out;

    rnn_mfma<<<dim3(2048 / BN), dim3(NT), 0, stream>>>(
        x, W_hx, W_hh, W_ph, b_h, b_p, out);
}

// Round 10
// 330.440 us; speedup vs baseline: 1.0501x; 1.0501x over previous
//
#include <hip/hip_runtime.h>

// VanillaRNN: S=512, I=1, H=256, C=10, B=2048, fp32 in/out.
// R10 = R6 verbatim: the empirically best configuration (290 us kernel).
// Elimination series R7-R9 proved: (a) LDS bank conflicts are off the
// critical path (R8 cut them 4x -> +0); (b) MFMA dep-chain depth and
// C-operand prefetch are off the critical path (R9 -> -5%); (c) b64 vs
// b128 access width is a wash. Step time ~1400 cyc is pinned by the
// barrier-locked step skeleton: barrier drain -> read latency -> fixed
// per-wave B-ingest (8x b128 = 128 B/lane, set by MFMA fragment size) ->
// phase-locked trans/epilogue tail -> write -> barrier; the all-to-all h
// dependency makes one full barrier per step semantically irreducible.
// Structure: 128 blocks x 8 waves (2/SIMD TLP), 2 m-tiles/wave, C-operand
// carries b_h + W_hx*x_t, x prefetch, weights pre-scaled by 2*log2e,
// tanh = 1 - 2*rcp(exp2(s)+1), hT chunk-xor swizzle (c ^ (n&7)).
// waves_per_eu(2,2): 256-VGPR budget, no spill (R1/R2 lesson).

#define SEQ   512
#define HID   256
#define NCLS  10
#define BN    16      // batch per block
#define NT    512     // 8 waves

typedef _Float16 f16x8 __attribute__((ext_vector_type(8)));
typedef _Float16 f16x4 __attribute__((ext_vector_type(4)));
typedef float    f32x4 __attribute__((ext_vector_type(4)));

__global__ __launch_bounds__(NT)
__attribute__((amdgpu_waves_per_eu(2, 2)))
void rnn_mfma(
    const float* __restrict__ x,     // [B, S]
    const float* __restrict__ W_hx,  // [H]
    const float* __restrict__ W_hh,  // [H, H]
    const float* __restrict__ W_ph,  // [C, H]
    const float* __restrict__ b_h,   // [H]
    const float* __restrict__ b_p,   // [C]
    float* __restrict__ out)         // [B, C]
{
    // hT[buf][n][k]: k-chunk c (8 f16) stored at physical chunk c ^ (n&7)
    __shared__ __align__(16) _Float16 hT[2][BN][HID];    // 16 KB
    __shared__ __align__(16) float xs[SEQ + 2][BN];      // 32.9 KB

    const int tid  = threadIdx.x;
    const int lane = tid & 63;
    const int wave = tid >> 6;       // 0..7
    const int n16  = lane & 15;
    const int quad = lane >> 4;      // 0..3
    const int e    = n16 & 7;
    const int b0   = blockIdx.x * BN;

    const float SC = 2.885390081777926814f;   // 2*log2(e)

    // ---- A-frags: rows [wave*32, wave*32+32), pre-scaled by SC, f16 ----
    // A[m = n16][k = quad*8 + j]
    f16x8 afrag[2][8];
#pragma unroll
    for (int mt = 0; mt < 2; ++mt) {
        const int row = wave * 32 + mt * 16 + n16;
#pragma unroll
        for (int ks = 0; ks < 8; ++ks) {
            const float4* p = (const float4*)&W_hh[row * HID + ks * 32 + quad * 8];
            float4 u = p[0], v = p[1];
            f16x8 a;
            a[0] = (_Float16)(SC * u.x); a[1] = (_Float16)(SC * u.y);
            a[2] = (_Float16)(SC * u.z); a[3] = (_Float16)(SC * u.w);
            a[4] = (_Float16)(SC * v.x); a[5] = (_Float16)(SC * v.y);
            a[6] = (_Float16)(SC * v.z); a[7] = (_Float16)(SC * v.w);
            afrag[mt][ks] = a;
        }
    }
    // D rows for this lane: row = wave*32 + mt*16 + quad*4 + r
    f32x4 bias[2], wxv[2];
#pragma unroll
    for (int mt = 0; mt < 2; ++mt)
#pragma unroll
        for (int r = 0; r < 4; ++r) {
            const int row = wave * 32 + mt * 16 + quad * 4 + r;
            bias[mt][r] = SC * b_h[row];
            wxv[mt][r]  = SC * W_hx[row];
        }

    // ---- precomputed swizzled byte offsets (within one buffer) ----
    int roff[8], woff[2];
#pragma unroll
    for (int ks = 0; ks < 8; ++ks)
        roff[ks] = (n16 * HID + (((4 * ks + quad) ^ e) << 3)) * 2;
#pragma unroll
    for (int mt = 0; mt < 2; ++mt)
        woff[mt] = (n16 * HID +
                    (((4 * wave + 2 * mt + (quad >> 1)) ^ e) << 3) +
                    (quad & 1) * 4) * 2;

    // ---- stage xs[t][n] = x[b0+n][t] ----
    for (int i = tid; i < BN * SEQ / 4; i += NT) {
        const int n = i >> 7, t4 = (i & 127) * 4;
        float4 v = *(const float4*)&x[(b0 + n) * SEQ + t4];
        xs[t4 + 0][n] = v.x; xs[t4 + 1][n] = v.y;
        xs[t4 + 2][n] = v.z; xs[t4 + 3][n] = v.w;
    }
    // ---- h0 = 0 (buffer 0 only; buffer 1 fully written each odd step) ----
    for (int i = tid; i < BN * HID / 2; i += NT) ((float*)hT[0])[i] = 0.0f;
    __syncthreads();

    float xv = xs[0][n16];   // prefetched x_t for step 0

#define RNN_STEP(T, RD, WR)                                                   \
    {                                                                         \
        const float xnxt = xs[(T) + 1][n16];  /* prefetch next step's x */    \
        const char* hb = (const char*)hT[RD];                                 \
        f16x8 bfr[8];                                                         \
        _Pragma("unroll")                                                     \
        for (int ks = 0; ks < 8; ++ks)                                        \
            bfr[ks] = *(const f16x8*)(hb + roff[ks]);                         \
        f32x4 acc[2];                                                         \
        _Pragma("unroll")                                                     \
        for (int mt = 0; mt < 2; ++mt) {                                      \
            f32x4 c0;                                                         \
            _Pragma("unroll")                                                 \
            for (int r = 0; r < 4; ++r)                                       \
                c0[r] = fmaf(wxv[mt][r], xv, bias[mt][r]);                    \
            acc[mt] = __builtin_amdgcn_mfma_f32_16x16x32_f16(                 \
                afrag[mt][0], bfr[0], c0, 0, 0, 0);                           \
        }                                                                     \
        _Pragma("unroll")                                                     \
        for (int ks = 1; ks < 8; ++ks)                                        \
            _Pragma("unroll")                                                 \
            for (int mt = 0; mt < 2; ++mt)                                    \
                acc[mt] = __builtin_amdgcn_mfma_f32_16x16x32_f16(             \
                    afrag[mt][ks], bfr[ks], acc[mt], 0, 0, 0);                \
        char* wb = (char*)hT[WR];                                             \
        _Pragma("unroll")                                                     \
        for (int mt = 0; mt < 2; ++mt) {                                      \
            f16x4 h4;                                                         \
            _Pragma("unroll")                                                 \
            for (int r = 0; r < 4; ++r) {                                     \
                float ex = __builtin_amdgcn_exp2f(acc[mt][r]);                \
                float rc = __builtin_amdgcn_rcpf(ex + 1.0f);                  \
                h4[r] = (_Float16)(1.0f - 2.0f * rc);                         \
            }                                                                 \
            *(f16x4*)(wb + woff[mt]) = h4;                                    \
        }                                                                     \
        xv = xnxt;                                                            \
        __syncthreads();                                                      \
    }

    for (int t = 0; t < SEQ; t += 2) {
        RNN_STEP(t, 0, 1);
        RNN_STEP(t + 1, 1, 0);
    }
#undef RNN_STEP

    // ---- output: out[b][c] = b_p[c] + sum_j W_ph[c][j] * h_final[j][b] ----
    // final h in hT[0]; element (n=b, k=j) at chunk (j>>3)^(b&7)
    if (tid < BN * NCLS) {
        const int b = tid / NCLS, c = tid % NCLS;
        float sum = b_p[c];
        const _Float16* hp = hT[0][b];
        for (int j = 0; j < HID; ++j) {
            const int ph = ((((j >> 3) ^ (b & 7)) << 3) | (j & 7));
            sum += W_ph[c * HID + j] * (float)hp[ph];
        }
        out[(b0 + b) * NCLS + c] = sum;
    }
}

extern "C" void kernel_launch(void* const* d_in, const int* in_sizes, int n_in,
                              void* d_out, int out_size, void* d_ws, size_t ws_size,
                              hipStream_t stream) {
    const float* x    = (const float*)d_in[0];
    const float* W_hx = (const float*)d_in[1];
    const float* W_hh = (const float*)d_in[2];
    const float* W_ph = (const float*)d_in[3];
    const float* b_h  = (const float*)d_in[4];
    const float* b_p  = (const float*)d_in[5];
    float* out = (float*)d_out;

    rnn_mfma<<<dim3(2048 / BN), dim3(NT), 0, stream>>>(
        x, W_hx, W_hh, W_ph, b_h, b_p, out);
}